// Round 1
// baseline (319.817 us; speedup 1.0000x reference)
//
#include <hip/hip_runtime.h>

// ExpertsPreferredMaskedRouter on MI355X
// Outputs (flat f32 in d_out): dispatch [G,T,E,cap], combine [G,T,E,cap],
// aux_loss, z_loss, causal_loss.

#define NEXP 8

// ---------------- zero fill ----------------
__global__ __launch_bounds__(256) void fill_zero_kernel(float* __restrict__ out, long long n) {
    long long i = (long long)blockIdx.x * blockDim.x + threadIdx.x;
    long long n4 = n >> 2;
    long long stride = (long long)gridDim.x * blockDim.x;
    for (long long k = i; k < n4; k += stride) {
        reinterpret_cast<float4*>(out)[k] = make_float4(0.f, 0.f, 0.f, 0.f);
    }
    if (i == 0) {
        for (long long k = n4 << 2; k < n; ++k) out[k] = 0.f;
    }
}

// ---------------- phase A: logits -> probs + z accumulation ----------------
// one wave (64 lanes) per token; 8 waves per block; W staged in LDS.
__global__ __launch_bounds__(512) void probs_kernel(
    const float* __restrict__ x,      // [GT, 1024]
    const float* __restrict__ w,      // [8, 1024]
    const float* __restrict__ bias,   // [8]
    float* __restrict__ probs,        // [GT, 8]
    double* __restrict__ zsum)
{
    __shared__ float wl[NEXP * 1024];
    // cooperative load of W (8192 floats = 2048 float4, 512 threads -> 4 each)
    for (int i = threadIdx.x; i < NEXP * 1024 / 4; i += 512) {
        reinterpret_cast<float4*>(wl)[i] = reinterpret_cast<const float4*>(w)[i];
    }
    __syncthreads();

    const int wave = threadIdx.x >> 6;
    const int lane = threadIdx.x & 63;
    const long long t = (long long)blockIdx.x * 8 + wave;
    const float* xr = x + t * 1024;

    float acc[NEXP];
#pragma unroll
    for (int e = 0; e < NEXP; ++e) acc[e] = 0.f;

#pragma unroll
    for (int c = 0; c < 4; ++c) {
        const int d = c * 256 + lane * 4;
        const float4 xv = *reinterpret_cast<const float4*>(xr + d);
#pragma unroll
        for (int e = 0; e < NEXP; ++e) {
            const float4 wv = *reinterpret_cast<const float4*>(wl + e * 1024 + d);
            acc[e] = fmaf(xv.x, wv.x, acc[e]);
            acc[e] = fmaf(xv.y, wv.y, acc[e]);
            acc[e] = fmaf(xv.z, wv.z, acc[e]);
            acc[e] = fmaf(xv.w, wv.w, acc[e]);
        }
    }
    // wave reduction (64 lanes)
#pragma unroll
    for (int e = 0; e < NEXP; ++e) {
#pragma unroll
        for (int off = 32; off; off >>= 1) acc[e] += __shfl_xor(acc[e], off, 64);
    }

    if (lane == 0) {
        double l[NEXP];
        double mx = -1e300;
#pragma unroll
        for (int e = 0; e < NEXP; ++e) {
            l[e] = (double)acc[e] + (double)bias[e];
            mx = fmax(mx, l[e]);
        }
        double ex[NEXP];
        double s = 0.0;
#pragma unroll
        for (int e = 0; e < NEXP; ++e) { ex[e] = exp(l[e] - mx); s += ex[e]; }
        const double inv = 1.0 / s;
#pragma unroll
        for (int e = 0; e < NEXP; ++e) probs[t * NEXP + e] = (float)(ex[e] * inv);
        const double lse = mx + log(s);
        atomicAdd(zsum, lse * lse);
    }
}

// ---------------- phase B: experts-preferred routing ----------------
// one block per group g. T=2048 tokens, 1024 threads (2 tokens/thread).
// For each expert in order: build 64-bit keys (value<<32 | ~idx), full
// bitonic descending sort in LDS (exact lax.top_k tie-break: value desc,
// index asc), scatter top-cap into d_out, mark picked tokens unavailable.
__global__ __launch_bounds__(1024) void routing_kernel(
    const float* __restrict__ probs,   // [GT, 8]
    const double* __restrict__ zsum,
    float* __restrict__ out,
    int T,            // 2048
    int cap,          // 320
    long long GT)     // 8192
{
    const int g = blockIdx.x;
    const int tid = threadIdx.x;

    __shared__ unsigned long long keys[2048];
    __shared__ int avail[2048];

    // per-thread register copy of this group's probs (2 tokens x 8 experts)
    float p0[NEXP], p1[NEXP];
    const float* pr = probs + ((long long)g * T) * NEXP;
#pragma unroll
    for (int e = 0; e < NEXP; ++e) {
        p0[e] = pr[(long long)tid * NEXP + e];
        p1[e] = pr[(long long)(tid + 1024) * NEXP + e];
    }
    avail[tid] = 1;
    avail[tid + 1024] = 1;

    float* dispatch = out;
    float* combine  = out + GT * NEXP * (long long)cap;

    for (int e = 0; e < NEXP; ++e) {
        __syncthreads();  // avail updates from previous expert visible

        const float v0 = avail[tid] ? p0[e] : 0.0f;
        const float v1 = avail[tid + 1024] ? p1[e] : 0.0f;
        keys[tid] = ((unsigned long long)__float_as_uint(v0) << 32) |
                    (unsigned)(~(unsigned)tid);
        keys[tid + 1024] = ((unsigned long long)__float_as_uint(v1) << 32) |
                           (unsigned)(~(unsigned)(tid + 1024));

        // bitonic sort, descending on 64-bit key
        for (unsigned k = 2; k <= 2048; k <<= 1) {
            for (unsigned j = k >> 1; j > 0; j >>= 1) {
                __syncthreads();
#pragma unroll
                for (int rep = 0; rep < 2; ++rep) {
                    const unsigned i = (unsigned)tid + rep * 1024u;
                    const unsigned ixj = i ^ j;
                    if (ixj > i) {
                        const unsigned long long a = keys[i];
                        const unsigned long long b = keys[ixj];
                        const bool desc = ((i & k) == 0);
                        if (desc ? (a < b) : (a > b)) {
                            keys[i] = b;
                            keys[ixj] = a;
                        }
                    }
                }
            }
        }
        __syncthreads();

        for (int c = tid; c < cap; c += 1024) {
            const unsigned long long key = keys[c];
            const unsigned idx = ~(unsigned)key;           // token index
            const float val = __uint_as_float((unsigned)(key >> 32));
            const long long o = ((((long long)g * T + idx) * NEXP) + e) * (long long)cap + c;
            dispatch[o] = 1.0f;
            combine[o]  = val;
            avail[idx] = 0;
        }
    }

    if (g == 0 && tid == 0) {
        float* s = out + 2 * GT * NEXP * (long long)cap;
        s[0] = 0.0f;                                   // auxiliary_loss
        s[1] = (float)(zsum[0] / (double)GT);          // z_loss
        s[2] = 0.0f;                                   // router_causal_loss
    }
}

extern "C" void kernel_launch(void* const* d_in, const int* in_sizes, int n_in,
                              void* d_out, int out_size, void* d_ws, size_t ws_size,
                              hipStream_t stream) {
    (void)n_in; (void)ws_size;
    const float* x    = (const float*)d_in[0];
    const float* w    = (const float*)d_in[1];
    const float* bias = (const float*)d_in[2];
    // d_in[3] = expert_capacity (device scalar); derive cap from out_size instead.

    const int E = in_sizes[2];                 // 8
    const int D = in_sizes[1] / E;             // 1024
    const long long GT = (long long)in_sizes[0] / D;  // 8192
    const int T = 2048;                        // per reference setup
    const int G = (int)(GT / T);               // 4
    const int cap = (int)(((long long)out_size - 3) / (2 * GT * E));

    double* zsum = (double*)d_ws;
    float* probs = (float*)((char*)d_ws + 256);

    // zero the z accumulator (first 16B of ws) and the whole output
    fill_zero_kernel<<<1, 64, 0, stream>>>((float*)d_ws, 4);
    fill_zero_kernel<<<2048, 256, 0, stream>>>((float*)d_out, (long long)out_size);

    probs_kernel<<<(int)(GT / 8), 512, 0, stream>>>(x, w, bias, probs, zsum);

    routing_kernel<<<G, 1024, 0, stream>>>(probs, zsum, (float*)d_out, T, cap, GT);
}

// Round 2
// 181.103 us; speedup vs baseline: 1.7659x; 1.7659x over previous
//
#include <hip/hip_runtime.h>

#define NEXP 8
typedef unsigned long long u64;
typedef unsigned int u32;

// ---------------- zero fill ----------------
__global__ __launch_bounds__(256) void fill_zero_kernel(float* __restrict__ out, long long n) {
    long long i = (long long)blockIdx.x * blockDim.x + threadIdx.x;
    long long n4 = n >> 2;
    long long stride = (long long)gridDim.x * blockDim.x;
    for (long long k = i; k < n4; k += stride) {
        reinterpret_cast<float4*>(out)[k] = make_float4(0.f, 0.f, 0.f, 0.f);
    }
    if (i == 0) {
        for (long long k = n4 << 2; k < n; ++k) out[k] = 0.f;
    }
}

// ---------------- phase A: logits -> probsT + z accumulation ----------------
// one wave per token; 8 waves/block; W staged in LDS. probsT layout [E][G*T].
__global__ __launch_bounds__(512) void probs_kernel(
    const float* __restrict__ x,      // [GT, 1024]
    const float* __restrict__ w,      // [8, 1024]
    const float* __restrict__ bias,   // [8]
    float* __restrict__ probsT,       // [E][GT]
    double* __restrict__ zsum,
    long long GT)
{
    __shared__ float wl[NEXP * 1024];
    for (int i = threadIdx.x; i < NEXP * 1024 / 4; i += 512) {
        reinterpret_cast<float4*>(wl)[i] = reinterpret_cast<const float4*>(w)[i];
    }
    __syncthreads();

    const int wave = threadIdx.x >> 6;
    const int lane = threadIdx.x & 63;
    const long long t = (long long)blockIdx.x * 8 + wave;
    const float* xr = x + t * 1024;

    float acc[NEXP];
#pragma unroll
    for (int e = 0; e < NEXP; ++e) acc[e] = 0.f;

#pragma unroll
    for (int c = 0; c < 4; ++c) {
        const int d = c * 256 + lane * 4;
        const float4 xv = *reinterpret_cast<const float4*>(xr + d);
#pragma unroll
        for (int e = 0; e < NEXP; ++e) {
            const float4 wv = *reinterpret_cast<const float4*>(wl + e * 1024 + d);
            acc[e] = fmaf(xv.x, wv.x, acc[e]);
            acc[e] = fmaf(xv.y, wv.y, acc[e]);
            acc[e] = fmaf(xv.z, wv.z, acc[e]);
            acc[e] = fmaf(xv.w, wv.w, acc[e]);
        }
    }
#pragma unroll
    for (int e = 0; e < NEXP; ++e) {
#pragma unroll
        for (int off = 32; off; off >>= 1) acc[e] += __shfl_xor(acc[e], off, 64);
    }

    if (lane == 0) {
        double l[NEXP];
        double mx = -1e300;
#pragma unroll
        for (int e = 0; e < NEXP; ++e) {
            l[e] = (double)acc[e] + (double)bias[e];
            mx = fmax(mx, l[e]);
        }
        double ex[NEXP];
        double s = 0.0;
#pragma unroll
        for (int e = 0; e < NEXP; ++e) { ex[e] = exp(l[e] - mx); s += ex[e]; }
        const double inv = 1.0 / s;
#pragma unroll
        for (int e = 0; e < NEXP; ++e) probsT[(long long)e * GT + t] = (float)(ex[e] * inv);
        const double lse = mx + log(s);
        atomicAdd(zsum, lse * lse);
    }
}

// ---------------- phase B1: per-(e,g) argsort by rank counting ----------------
// key = bits(p)<<32 | ~idx  (desc u64 order == value desc, idx asc).
// grid = E*G*(T/256) blocks of 256; block `sub` ranks tokens [256*sub, 256*sub+256).
__global__ __launch_bounds__(256) void ranksort_kernel(
    const float* __restrict__ probsT,  // [E][GT]
    u64* __restrict__ skey,            // [E*G][T], skey[pair][rank] = key
    int T, int G, long long GT)
{
    __shared__ u64 keys[2048];
    const int nsub = T / 256;
    const int pair = blockIdx.x / nsub;   // e*G + g
    const int sub  = blockIdx.x % nsub;
    const int e = pair / G;
    const int g = pair % G;
    const float* p = probsT + (long long)e * GT + (long long)g * T;

    for (int j = threadIdx.x; j < T; j += 256) {
        keys[j] = ((u64)__float_as_uint(p[j]) << 32) | (u32)(~(u32)j);
    }
    __syncthreads();

    const int i = sub * 256 + threadIdx.x;
    const u64 ki = keys[i];
    int r = 0;
    const ulonglong2* k2 = reinterpret_cast<const ulonglong2*>(keys);
#pragma unroll 8
    for (int j = 0; j < T / 2; ++j) {
        const ulonglong2 q = k2[j];
        r += (q.x > ki);
        r += (q.y > ki);
    }
    skey[(long long)pair * T + r] = ki;
}

// ---------------- phase B2: serial expert scan per group ----------------
// one block per group; 1024 threads handle 2048 sorted positions / tokens.
__global__ __launch_bounds__(1024) void assign_kernel(
    const u64* __restrict__ skey,   // [E*G][T]
    const double* __restrict__ zsum,
    float* __restrict__ out,
    int T, int G, int cap, long long GT)
{
    const int g = blockIdx.x;
    const int tid = threadIdx.x;
    const int lane = tid & 63;
    const int w = tid >> 6;

    __shared__ int avail[2048];
    __shared__ int cnt[32];
    __shared__ int off[32];
    __shared__ int totS;

    avail[tid] = 1;
    avail[tid + 1024] = 1;

    float* dispatch = out;
    float* combine  = out + GT * (long long)NEXP * cap;
    const long long gbase = (long long)g * T;
    const u64 lmask = (lane == 0) ? 0ull : ((~0ull) >> (64 - lane));

    for (int e = 0; e < NEXP; ++e) {
        __syncthreads();  // prior expert's avail updates visible
        const long long kb = (long long)(e * G + g) * T;
        const u64 k0 = skey[kb + tid];
        const u64 k1 = skey[kb + tid + 1024];
        const u32 idx0 = ~(u32)k0;
        const u32 idx1 = ~(u32)k1;
        const float v0 = __uint_as_float((u32)(k0 >> 32));
        const float v1 = __uint_as_float((u32)(k1 >> 32));
        const int f0 = avail[idx0];
        const int f1 = avail[idx1];
        const u64 m0 = __ballot(f0);
        const u64 m1 = __ballot(f1);
        if (lane == 0) { cnt[w] = __popcll(m0); cnt[16 + w] = __popcll(m1); }
        __syncthreads();
        if (w == 0) {
            int v = (lane < 32) ? cnt[lane] : 0;
#pragma unroll
            for (int o = 1; o < 32; o <<= 1) { int t2 = __shfl_up(v, o, 64); if (lane >= o) v += t2; }
            if (lane < 32) off[lane] = v - cnt[lane];
            if (lane == 31) totS = v;
        }
        __syncthreads();
        const int S = totS;
        const int pre0 = off[w] + __popcll(m0 & lmask);
        const int pre1 = off[16 + w] + __popcll(m1 & lmask);
        const bool s0 = f0 && pre0 < cap;
        const bool s1 = f1 && pre1 < cap;
        if (s0) {
            const long long o_ = ((gbase + idx0) * NEXP + e) * (long long)cap + pre0;
            dispatch[o_] = 1.0f;
            combine[o_]  = v0;
        }
        if (s1) {
            const long long o_ = ((gbase + idx1) * NEXP + e) * (long long)cap + pre1;
            dispatch[o_] = 1.0f;
            combine[o_]  = v1;
        }
        if (S < cap) {
            // zero-value fill: smallest-index unavailable tokens (combine stays 0)
            const int u0 = 1 - avail[tid];
            const int u1 = 1 - avail[tid + 1024];
            const u64 n0 = __ballot(u0);
            const u64 n1 = __ballot(u1);
            if (lane == 0) { cnt[w] = __popcll(n0); cnt[16 + w] = __popcll(n1); }
            __syncthreads();
            if (w == 0) {
                int v = (lane < 32) ? cnt[lane] : 0;
#pragma unroll
                for (int o = 1; o < 32; o <<= 1) { int t2 = __shfl_up(v, o, 64); if (lane >= o) v += t2; }
                if (lane < 32) off[lane] = v - cnt[lane];
            }
            __syncthreads();
            const int q0 = off[w] + __popcll(n0 & lmask);
            const int q1 = off[16 + w] + __popcll(n1 & lmask);
            const int nfill = cap - S;
            if (u0 && q0 < nfill) {
                const long long o_ = ((gbase + tid) * NEXP + e) * (long long)cap + S + q0;
                dispatch[o_] = 1.0f;
            }
            if (u1 && q1 < nfill) {
                const long long o_ = ((gbase + tid + 1024) * NEXP + e) * (long long)cap + S + q1;
                dispatch[o_] = 1.0f;
            }
        }
        __syncthreads();  // all avail reads (incl. zero-fill) done before updates
        if (s0) avail[idx0] = 0;
        if (s1) avail[idx1] = 0;
    }

    if (g == 0 && tid == 0) {
        float* s = out + 2 * GT * (long long)NEXP * cap;
        s[0] = 0.0f;
        s[1] = (float)(zsum[0] / (double)GT);
        s[2] = 0.0f;
    }
}

extern "C" void kernel_launch(void* const* d_in, const int* in_sizes, int n_in,
                              void* d_out, int out_size, void* d_ws, size_t ws_size,
                              hipStream_t stream) {
    (void)n_in; (void)ws_size;
    const float* x    = (const float*)d_in[0];
    const float* w    = (const float*)d_in[1];
    const float* bias = (const float*)d_in[2];

    const int E = in_sizes[2];                        // 8
    const int D = in_sizes[1] / E;                    // 1024
    const long long GT = (long long)in_sizes[0] / D;  // 8192
    const int T = 2048;
    const int G = (int)(GT / T);                      // 4
    const int cap = (int)(((long long)out_size - 3) / (2 * GT * E));

    double* zsum  = (double*)d_ws;
    float* probsT = (float*)((char*)d_ws + 4096);
    u64*   skey   = (u64*)((char*)d_ws + 4096 + (size_t)E * GT * sizeof(float));

    fill_zero_kernel<<<1, 64, 0, stream>>>((float*)d_ws, 4);
    fill_zero_kernel<<<2048, 256, 0, stream>>>((float*)d_out, (long long)out_size);

    probs_kernel<<<(int)(GT / 8), 512, 0, stream>>>(x, w, bias, probsT, zsum, GT);

    ranksort_kernel<<<E * G * (T / 256), 256, 0, stream>>>(probsT, skey, T, G, GT);

    assign_kernel<<<G, 1024, 0, stream>>>(skey, zsum, (float*)d_out, T, G, cap, GT);
}

// Round 3
// 91.298 us; speedup vs baseline: 3.5030x; 1.9837x over previous
//
#include <hip/hip_runtime.h>

#define NEXP 8
typedef unsigned long long u64;
typedef unsigned int u32;

// ---------------- zero fill ----------------
__global__ __launch_bounds__(256) void fill_zero_kernel(float* __restrict__ out, long long n) {
    long long i = (long long)blockIdx.x * blockDim.x + threadIdx.x;
    long long n4 = n >> 2;
    long long stride = (long long)gridDim.x * blockDim.x;
    for (long long k = i; k < n4; k += stride) {
        reinterpret_cast<float4*>(out)[k] = make_float4(0.f, 0.f, 0.f, 0.f);
    }
    if (i == 0) {
        for (long long k = n4 << 2; k < n; ++k) out[k] = 0.f;
    }
}

// ---------------- phase A: logits -> probsT + per-block z partials ----------
// one wave per token; 8 waves/block; W staged in LDS. probsT layout [E][GT].
__global__ __launch_bounds__(512) void probs_kernel(
    const float* __restrict__ x,      // [GT, 1024]
    const float* __restrict__ w,      // [8, 1024]
    const float* __restrict__ bias,   // [8]
    float* __restrict__ probsT,       // [E][GT]
    double* __restrict__ zpart,       // [gridDim.x]
    long long GT)
{
    __shared__ float wl[NEXP * 1024];
    __shared__ double zred[8];
    for (int i = threadIdx.x; i < NEXP * 1024 / 4; i += 512) {
        reinterpret_cast<float4*>(wl)[i] = reinterpret_cast<const float4*>(w)[i];
    }
    __syncthreads();

    const int wave = threadIdx.x >> 6;
    const int lane = threadIdx.x & 63;
    const long long t = (long long)blockIdx.x * 8 + wave;
    const float* xr = x + t * 1024;

    float acc[NEXP];
#pragma unroll
    for (int e = 0; e < NEXP; ++e) acc[e] = 0.f;

#pragma unroll
    for (int c = 0; c < 4; ++c) {
        const int d = c * 256 + lane * 4;
        const float4 xv = *reinterpret_cast<const float4*>(xr + d);
#pragma unroll
        for (int e = 0; e < NEXP; ++e) {
            const float4 wv = *reinterpret_cast<const float4*>(wl + e * 1024 + d);
            acc[e] = fmaf(xv.x, wv.x, acc[e]);
            acc[e] = fmaf(xv.y, wv.y, acc[e]);
            acc[e] = fmaf(xv.z, wv.z, acc[e]);
            acc[e] = fmaf(xv.w, wv.w, acc[e]);
        }
    }
#pragma unroll
    for (int e = 0; e < NEXP; ++e) {
#pragma unroll
        for (int off = 32; off; off >>= 1) acc[e] += __shfl_xor(acc[e], off, 64);
    }

    if (lane == 0) {
        double l[NEXP];
        double mx = -1e300;
#pragma unroll
        for (int e = 0; e < NEXP; ++e) {
            l[e] = (double)acc[e] + (double)bias[e];
            mx = fmax(mx, l[e]);
        }
        double ex[NEXP];
        double s = 0.0;
#pragma unroll
        for (int e = 0; e < NEXP; ++e) { ex[e] = exp(l[e] - mx); s += ex[e]; }
        const double inv = 1.0 / s;
#pragma unroll
        for (int e = 0; e < NEXP; ++e) probsT[(long long)e * GT + t] = (float)(ex[e] * inv);
        const double lse = mx + log(s);
        zred[wave] = lse * lse;
    }
    __syncthreads();
    if (threadIdx.x == 0) {
        double s = 0.0;
#pragma unroll
        for (int i = 0; i < 8; ++i) s += zred[i];
        zpart[blockIdx.x] = s;
    }
}

// ---------------- phase B1: per-(e,g) argsort by rank counting ----------------
__global__ __launch_bounds__(256) void ranksort_kernel(
    const float* __restrict__ probsT,  // [E][GT]
    u64* __restrict__ skey,            // [E*G][T]
    int T, int G, long long GT)
{
    __shared__ u64 keys[2048];
    const int nsub = T / 256;
    const int pair = blockIdx.x / nsub;   // e*G + g
    const int sub  = blockIdx.x % nsub;
    const int e = pair / G;
    const int g = pair % G;
    const float* p = probsT + (long long)e * GT + (long long)g * T;

    for (int j = threadIdx.x; j < T; j += 256) {
        keys[j] = ((u64)__float_as_uint(p[j]) << 32) | (u32)(~(u32)j);
    }
    __syncthreads();

    const int i = sub * 256 + threadIdx.x;
    const u64 ki = keys[i];
    int r = 0;
    const ulonglong2* k2 = reinterpret_cast<const ulonglong2*>(keys);
#pragma unroll 8
    for (int j = 0; j < T / 2; ++j) {
        const ulonglong2 q = k2[j];
        r += (q.x > ki);
        r += (q.y > ki);
    }
    skey[(long long)pair * T + r] = ki;
}

// ---------------- phase B2: serial expert scan per group ----------------
__global__ __launch_bounds__(1024) void assign_kernel(
    const u64* __restrict__ skey,   // [E*G][T]
    const double* __restrict__ zpart,
    int nzpart,
    float* __restrict__ out,
    int T, int G, int cap, long long GT)
{
    const int g = blockIdx.x;
    const int tid = threadIdx.x;
    const int lane = tid & 63;
    const int w = tid >> 6;

    __shared__ int avail[2048];
    __shared__ int cnt[32];
    __shared__ int off[32];
    __shared__ int totS;

    avail[tid] = 1;
    avail[tid + 1024] = 1;

    float* dispatch = out;
    float* combine  = out + GT * (long long)NEXP * cap;
    const long long gbase = (long long)g * T;
    const u64 lmask = (lane == 0) ? 0ull : ((~0ull) >> (64 - lane));

    for (int e = 0; e < NEXP; ++e) {
        __syncthreads();
        const long long kb = (long long)(e * G + g) * T;
        const u64 k0 = skey[kb + tid];
        const u64 k1 = skey[kb + tid + 1024];
        const u32 idx0 = ~(u32)k0;
        const u32 idx1 = ~(u32)k1;
        const float v0 = __uint_as_float((u32)(k0 >> 32));
        const float v1 = __uint_as_float((u32)(k1 >> 32));
        const int f0 = avail[idx0];
        const int f1 = avail[idx1];
        const u64 m0 = __ballot(f0);
        const u64 m1 = __ballot(f1);
        if (lane == 0) { cnt[w] = __popcll(m0); cnt[16 + w] = __popcll(m1); }
        __syncthreads();
        if (w == 0) {
            int v = (lane < 32) ? cnt[lane] : 0;
#pragma unroll
            for (int o = 1; o < 32; o <<= 1) { int t2 = __shfl_up(v, o, 64); if (lane >= o) v += t2; }
            if (lane < 32) off[lane] = v - cnt[lane];
            if (lane == 31) totS = v;
        }
        __syncthreads();
        const int S = totS;
        const int pre0 = off[w] + __popcll(m0 & lmask);
        const int pre1 = off[16 + w] + __popcll(m1 & lmask);
        const bool s0 = f0 && pre0 < cap;
        const bool s1 = f1 && pre1 < cap;
        if (s0) {
            const long long o_ = ((gbase + idx0) * NEXP + e) * (long long)cap + pre0;
            dispatch[o_] = 1.0f;
            combine[o_]  = v0;
        }
        if (s1) {
            const long long o_ = ((gbase + idx1) * NEXP + e) * (long long)cap + pre1;
            dispatch[o_] = 1.0f;
            combine[o_]  = v1;
        }
        if (S < cap) {
            const int u0 = 1 - avail[tid];
            const int u1 = 1 - avail[tid + 1024];
            const u64 n0 = __ballot(u0);
            const u64 n1 = __ballot(u1);
            if (lane == 0) { cnt[w] = __popcll(n0); cnt[16 + w] = __popcll(n1); }
            __syncthreads();
            if (w == 0) {
                int v = (lane < 32) ? cnt[lane] : 0;
#pragma unroll
                for (int o = 1; o < 32; o <<= 1) { int t2 = __shfl_up(v, o, 64); if (lane >= o) v += t2; }
                if (lane < 32) off[lane] = v - cnt[lane];
            }
            __syncthreads();
            const int q0 = off[w] + __popcll(n0 & lmask);
            const int q1 = off[16 + w] + __popcll(n1 & lmask);
            const int nfill = cap - S;
            if (u0 && q0 < nfill) {
                const long long o_ = ((gbase + tid) * NEXP + e) * (long long)cap + S + q0;
                dispatch[o_] = 1.0f;
            }
            if (u1 && q1 < nfill) {
                const long long o_ = ((gbase + tid + 1024) * NEXP + e) * (long long)cap + S + q1;
                dispatch[o_] = 1.0f;
            }
        }
        __syncthreads();
        if (s0) avail[idx0] = 0;
        if (s1) avail[idx1] = 0;
    }

    // z_loss: one wave of block 0 sums the per-block partials
    if (g == 0 && tid < 64) {
        double s = 0.0;
        for (int i = tid; i < nzpart; i += 64) s += zpart[i];
#pragma unroll
        for (int o = 32; o; o >>= 1) {
            s += __shfl_xor(s, o, 64);
        }
        if (tid == 0) {
            float* sc = out + 2 * GT * (long long)NEXP * cap;
            sc[0] = 0.0f;
            sc[1] = (float)(s / (double)GT);
            sc[2] = 0.0f;
        }
    }
}

extern "C" void kernel_launch(void* const* d_in, const int* in_sizes, int n_in,
                              void* d_out, int out_size, void* d_ws, size_t ws_size,
                              hipStream_t stream) {
    (void)n_in; (void)ws_size;
    const float* x    = (const float*)d_in[0];
    const float* w    = (const float*)d_in[1];
    const float* bias = (const float*)d_in[2];

    const int E = in_sizes[2];                        // 8
    const int D = in_sizes[1] / E;                    // 1024
    const long long GT = (long long)in_sizes[0] / D;  // 8192
    const int T = 2048;
    const int G = (int)(GT / T);                      // 4
    const int cap = (int)(((long long)out_size - 3) / (2 * GT * E));
    const int nblk = (int)(GT / 8);                   // 1024 probs blocks

    double* zpart = (double*)d_ws;                                 // 8 KB
    float* probsT = (float*)((char*)d_ws + 16384);                 // E*GT*4
    u64*   skey   = (u64*)((char*)d_ws + 16384 + (size_t)E * GT * sizeof(float));

    fill_zero_kernel<<<2048, 256, 0, stream>>>((float*)d_out, (long long)out_size);

    probs_kernel<<<nblk, 512, 0, stream>>>(x, w, bias, probsT, zpart, GT);

    ranksort_kernel<<<E * G * (T / 256), 256, 0, stream>>>(probsT, skey, T, G, GT);

    assign_kernel<<<G, 1024, 0, stream>>>(skey, zpart, nblk, (float*)d_out, T, G, cap, GT);
}

// Round 4
// 80.126 us; speedup vs baseline: 3.9914x; 1.1394x over previous
//
#include <hip/hip_runtime.h>

#define NEXP 8
typedef unsigned long long u64;
typedef unsigned int u32;

// ---------------- fused: probs (blocks [0,npb)) + zero-fill (rest) ----------
// probs: one wave per token; 8 waves/block; W staged in LDS. probsT [E][GT].
__global__ __launch_bounds__(512) void probs_fill_kernel(
    const float* __restrict__ x,      // [GT, 1024]
    const float* __restrict__ w,      // [8, 1024]
    const float* __restrict__ bias,   // [8]
    float* __restrict__ probsT,       // [E][GT]
    double* __restrict__ zpart,       // [npb]
    float* __restrict__ out,
    long long nout4,                  // float4 count of d_out (excl. 3-scalar tail)
    long long GT, int npb, int nfb)
{
    if ((int)blockIdx.x >= npb) {
        // ---- zero-fill path: no LDS, no barriers ----
        const int fb = (int)blockIdx.x - npb;
        const long long stride = (long long)nfb * 512;
        const float4 z = make_float4(0.f, 0.f, 0.f, 0.f);
        for (long long k = (long long)fb * 512 + threadIdx.x; k < nout4; k += stride) {
            reinterpret_cast<float4*>(out)[k] = z;
        }
        return;
    }

    // ---- probs path ----
    __shared__ float wl[NEXP * 1024];
    __shared__ double zred[8];
    for (int i = threadIdx.x; i < NEXP * 1024 / 4; i += 512) {
        reinterpret_cast<float4*>(wl)[i] = reinterpret_cast<const float4*>(w)[i];
    }
    __syncthreads();

    const int wave = threadIdx.x >> 6;
    const int lane = threadIdx.x & 63;
    const long long t = (long long)blockIdx.x * 8 + wave;
    const float* xr = x + t * 1024;

    float acc[NEXP];
#pragma unroll
    for (int e = 0; e < NEXP; ++e) acc[e] = 0.f;

#pragma unroll
    for (int c = 0; c < 4; ++c) {
        const int d = c * 256 + lane * 4;
        const float4 xv = *reinterpret_cast<const float4*>(xr + d);
#pragma unroll
        for (int e = 0; e < NEXP; ++e) {
            const float4 wv = *reinterpret_cast<const float4*>(wl + e * 1024 + d);
            acc[e] = fmaf(xv.x, wv.x, acc[e]);
            acc[e] = fmaf(xv.y, wv.y, acc[e]);
            acc[e] = fmaf(xv.z, wv.z, acc[e]);
            acc[e] = fmaf(xv.w, wv.w, acc[e]);
        }
    }
#pragma unroll
    for (int e = 0; e < NEXP; ++e) {
#pragma unroll
        for (int off = 32; off; off >>= 1) acc[e] += __shfl_xor(acc[e], off, 64);
    }

    if (lane == 0) {
        double l[NEXP];
        double mx = -1e300;
#pragma unroll
        for (int e = 0; e < NEXP; ++e) {
            l[e] = (double)acc[e] + (double)bias[e];
            mx = fmax(mx, l[e]);
        }
        double ex[NEXP];
        double s = 0.0;
#pragma unroll
        for (int e = 0; e < NEXP; ++e) { ex[e] = exp(l[e] - mx); s += ex[e]; }
        const double inv = 1.0 / s;
#pragma unroll
        for (int e = 0; e < NEXP; ++e) probsT[(long long)e * GT + t] = (float)(ex[e] * inv);
        const double lse = mx + log(s);
        zred[wave] = lse * lse;
    }
    __syncthreads();
    if (threadIdx.x == 0) {
        double s = 0.0;
#pragma unroll
        for (int i = 0; i < 8; ++i) s += zred[i];
        zpart[blockIdx.x] = s;
    }
}

// ---------------- phase B1: per-(e,g) argsort by rank counting ----------------
// key = bits(p)<<32 | ~idx  (desc u64 order == value desc, idx asc).
__global__ __launch_bounds__(256) void ranksort_kernel(
    const float* __restrict__ probsT,  // [E][GT]
    u64* __restrict__ skey,            // [E*G][T]
    int T, int G, long long GT)
{
    __shared__ u64 keys[2048];
    const int nsub = T / 256;
    const int pair = blockIdx.x / nsub;   // e*G + g
    const int sub  = blockIdx.x % nsub;
    const int e = pair / G;
    const int g = pair % G;
    const float* p = probsT + (long long)e * GT + (long long)g * T;

    for (int j = threadIdx.x; j < T; j += 256) {
        keys[j] = ((u64)__float_as_uint(p[j]) << 32) | (u32)(~(u32)j);
    }
    __syncthreads();

    const int i = sub * 256 + threadIdx.x;
    const u64 ki = keys[i];
    int r = 0;
    const ulonglong2* k2 = reinterpret_cast<const ulonglong2*>(keys);
#pragma unroll 8
    for (int j = 0; j < T / 2; ++j) {
        const ulonglong2 q = k2[j];
        r += (q.x > ki);
        r += (q.y > ki);
    }
    skey[(long long)pair * T + r] = ki;
}

// ---------------- phase B2: serial expert scan per group ----------------
__global__ __launch_bounds__(1024) void assign_kernel(
    const u64* __restrict__ skey,   // [E*G][T]
    const double* __restrict__ zpart,
    int nzpart,
    float* __restrict__ out,
    int T, int G, int cap, long long GT)
{
    const int g = blockIdx.x;
    const int tid = threadIdx.x;
    const int lane = tid & 63;
    const int w = tid >> 6;

    __shared__ int avail[2048];
    __shared__ int cnt[32];
    __shared__ int off[32];
    __shared__ int totS;

    avail[tid] = 1;
    avail[tid + 1024] = 1;

    float* dispatch = out;
    float* combine  = out + GT * (long long)NEXP * cap;
    const long long gbase = (long long)g * T;
    const u64 lmask = (lane == 0) ? 0ull : ((~0ull) >> (64 - lane));

    for (int e = 0; e < NEXP; ++e) {
        __syncthreads();  // prior expert's avail updates visible (B_top)
        const long long kb = (long long)(e * G + g) * T;
        const u64 k0 = skey[kb + tid];
        const u64 k1 = skey[kb + tid + 1024];
        const u32 idx0 = ~(u32)k0;
        const u32 idx1 = ~(u32)k1;
        const float v0 = __uint_as_float((u32)(k0 >> 32));
        const float v1 = __uint_as_float((u32)(k1 >> 32));
        const int f0 = avail[idx0];
        const int f1 = avail[idx1];
        const u64 m0 = __ballot(f0);
        const u64 m1 = __ballot(f1);
        if (lane == 0) { cnt[w] = __popcll(m0); cnt[16 + w] = __popcll(m1); }
        __syncthreads();  // B1
        if (w == 0) {
            int v = (lane < 32) ? cnt[lane] : 0;
#pragma unroll
            for (int o = 1; o < 32; o <<= 1) { int t2 = __shfl_up(v, o, 64); if (lane >= o) v += t2; }
            if (lane < 32) off[lane] = v - cnt[lane];
            if (lane == 31) totS = v;
        }
        __syncthreads();  // B2
        const int S = totS;
        const int pre0 = off[w] + __popcll(m0 & lmask);
        const int pre1 = off[16 + w] + __popcll(m1 & lmask);
        const bool s0 = f0 && pre0 < cap;
        const bool s1 = f1 && pre1 < cap;
        if (s0) {
            const long long o_ = ((gbase + idx0) * NEXP + e) * (long long)cap + pre0;
            dispatch[o_] = 1.0f;
            combine[o_]  = v0;
        }
        if (s1) {
            const long long o_ = ((gbase + idx1) * NEXP + e) * (long long)cap + pre1;
            dispatch[o_] = 1.0f;
            combine[o_]  = v1;
        }
        if (S < cap) {
            // zero-value fill: smallest-index unavailable tokens (combine stays 0)
            const int u0 = 1 - avail[tid];
            const int u1 = 1 - avail[tid + 1024];
            const u64 n0 = __ballot(u0);
            const u64 n1 = __ballot(u1);
            if (lane == 0) { cnt[w] = __popcll(n0); cnt[16 + w] = __popcll(n1); }
            __syncthreads();
            if (w == 0) {
                int v = (lane < 32) ? cnt[lane] : 0;
#pragma unroll
                for (int o = 1; o < 32; o <<= 1) { int t2 = __shfl_up(v, o, 64); if (lane >= o) v += t2; }
                if (lane < 32) off[lane] = v - cnt[lane];
            }
            __syncthreads();
            const int q0 = off[w] + __popcll(n0 & lmask);
            const int q1 = off[16 + w] + __popcll(n1 & lmask);
            const int nfill = cap - S;
            if (u0 && q0 < nfill) {
                const long long o_ = ((gbase + tid) * NEXP + e) * (long long)cap + S + q0;
                dispatch[o_] = 1.0f;
            }
            if (u1 && q1 < nfill) {
                const long long o_ = ((gbase + tid + 1024) * NEXP + e) * (long long)cap + S + q1;
                dispatch[o_] = 1.0f;
            }
            __syncthreads();  // B3: fill-path avail reads done before updates
        }
        // (for S>=cap all avail reads happened before B1; next B_top covers the hazard)
        if (s0) avail[idx0] = 0;
        if (s1) avail[idx1] = 0;
    }

    // z_loss: one wave of block 0 sums the per-block partials
    if (g == 0 && tid < 64) {
        double s = 0.0;
        for (int i = tid; i < nzpart; i += 64) s += zpart[i];
#pragma unroll
        for (int o = 32; o; o >>= 1) {
            s += __shfl_xor(s, o, 64);
        }
        if (tid == 0) {
            float* sc = out + 2 * GT * (long long)NEXP * cap;
            sc[0] = 0.0f;
            sc[1] = (float)(s / (double)GT);
            sc[2] = 0.0f;
        }
    }
}

extern "C" void kernel_launch(void* const* d_in, const int* in_sizes, int n_in,
                              void* d_out, int out_size, void* d_ws, size_t ws_size,
                              hipStream_t stream) {
    (void)n_in; (void)ws_size;
    const float* x    = (const float*)d_in[0];
    const float* w    = (const float*)d_in[1];
    const float* bias = (const float*)d_in[2];

    const int E = in_sizes[2];                        // 8
    const int D = in_sizes[1] / E;                    // 1024
    const long long GT = (long long)in_sizes[0] / D;  // 8192
    const int T = 2048;
    const int G = (int)(GT / T);                      // 4
    const int cap = (int)(((long long)out_size - 3) / (2 * GT * E));
    const int npb = (int)(GT / 8);                    // 1024 probs blocks
    const int nfb = 2048;                             // fill blocks

    double* zpart = (double*)d_ws;                                 // npb*8 B
    float* probsT = (float*)((char*)d_ws + 16384);                 // E*GT*4
    u64*   skey   = (u64*)((char*)d_ws + 16384 + (size_t)E * GT * sizeof(float));

    const long long nout4 = ((long long)out_size - 3) >> 2;        // float4 count

    probs_fill_kernel<<<npb + nfb, 512, 0, stream>>>(
        x, w, bias, probsT, zpart, (float*)d_out, nout4, GT, npb, nfb);

    ranksort_kernel<<<E * G * (T / 256), 256, 0, stream>>>(probsT, skey, T, G, GT);

    assign_kernel<<<G, 1024, 0, stream>>>(skey, zpart, npb, (float*)d_out, T, G, cap, GT);
}